// Round 5
// baseline (54.957 us; speedup 1.0000x reference)
//
#include <hip/hip_runtime.h>
#include <cmath>

#define HH 512
#define WW 512
#define TILE 64
#define S_IMG 72   // staged image stride (72x72, halo 4)
#define S_T  68    // stride for hblur / blurred / mag tiles (272B, 16B-aligned)
#define NT 256

struct Blur5 { float w[5]; };

// packed (dr+1),(dc+1) 2-bit LUTs for the 8 NMS directions
// OFFS = {(0,1),(-1,1),(-1,0),(-1,-1),(0,-1),(1,-1),(1,0),(1,1)}
#define DR_PACK 43265u
#define DC_PACK 36890u

__device__ __forceinline__ float4 ld4(const float* p) {
  return *reinterpret_cast<const float4*>(p);
}
__device__ __forceinline__ void st4(float* p, float4 v) {
  *reinterpret_cast<float4*>(p) = v;
}

// rc = jnp.round((degrees(atan2(gy,gx)) + 180)/45) in [0,8], via comparisons.
// Validated vs reference in R1/R2/R3 (absmax 0.0).
__device__ __forceinline__ int orient_bin(float gx, float gy) {
  const float T1 = 0.41421356237309503f;  // tan(22.5)
  const float T2 = 2.41421356237309503f;  // tan(67.5)
  float a = fabsf(gy), b = fabsf(gx);
  int sx = (int)(__float_as_uint(gx) >> 31);
  int sy = (int)(__float_as_uint(gy) >> 31);
  int rc;
  if (a <= T1 * b)      rc = sx ? (8 - 8 * sy) : 4;
  else if (a >= T2 * b) rc = 6 - 4 * sy;
  else                  rc = sx ? (7 - 6 * sy) : (5 - 2 * sy);
  return rc;
}

// ACC=false: store thin/rc into arrays.  ACC=true: accumulate loss vs arrays.
template<bool ACC>
__device__ __forceinline__ void canny_tile(
    const float* __restrict__ img, int base_r, int base_c,
    float* __restrict__ sA, float* __restrict__ sB, const Blur5& kb,
    float thin[16], int rcv[16], float& sAcc, int& soAcc)
{
  const int tid = threadIdx.x;
  const float k0 = kb.w[0], k1 = kb.w[1], k2 = kb.w[2], k3 = kb.w[3], k4 = kb.w[4];

  // ---- P1: stage 72x72 image tile (halo 4) as float4 groups ----
  // group = 4 consecutive cols; always fully inside or fully outside image.
  for (unsigned g = tid; g < 72u * 18u; g += NT) {
    unsigned r = g / 18u, k = g - r * 18u;
    int gr = base_r + (int)r - 4;
    int gcb = base_c + (int)(k * 4u) - 4;
    float4 v = {0.f, 0.f, 0.f, 0.f};
    if ((unsigned)gr < HH && (unsigned)gcb < WW)
      v = ld4(img + gr * WW + gcb);
    st4(&sA[r * S_IMG + k * 4u], v);
  }
  __syncthreads();

  // ---- P2: horizontal 5-tap blur -> sB [72][68] ----
  for (unsigned g = tid; g < 72u * 17u; g += NT) {
    unsigned r = g / 17u, k = g - r * 17u, c4 = k * 4u;
    const float* p = &sA[r * S_IMG + c4];
    float4 a = ld4(p), b = ld4(p + 4);
    float4 o;
    o.x = k0*a.x + k1*a.y + k2*a.z + k3*a.w + k4*b.x;
    o.y = k0*a.y + k1*a.z + k2*a.w + k3*b.x + k4*b.y;
    o.z = k0*a.z + k1*a.w + k2*b.x + k3*b.y + k4*b.z;
    o.w = k0*a.w + k1*b.x + k2*b.y + k3*b.z + k4*b.w;
    st4(&sB[r * S_T + c4], o);
  }
  __syncthreads();

  // ---- P3: vertical 5-tap blur -> sA [68][68]; zero outside image ----
  for (unsigned g = tid; g < 68u * 17u; g += NT) {
    unsigned r = g / 17u, k = g - r * 17u, c4 = k * 4u;
    const float* p = &sB[r * S_T + c4];
    float4 v0 = ld4(p), v1 = ld4(p + S_T), v2 = ld4(p + 2*S_T),
           v3 = ld4(p + 3*S_T), v4 = ld4(p + 4*S_T);
    float4 o;
    o.x = k0*v0.x + k1*v1.x + k2*v2.x + k3*v3.x + k4*v4.x;
    o.y = k0*v0.y + k1*v1.y + k2*v2.y + k3*v3.y + k4*v4.y;
    o.z = k0*v0.z + k1*v1.z + k2*v2.z + k3*v3.z + k4*v4.z;
    o.w = k0*v0.w + k1*v1.w + k2*v2.w + k3*v3.w + k4*v4.w;
    bool rok = (unsigned)(base_r + (int)r - 2) < HH;
    int gcb = base_c + (int)c4 - 2;
    o.x = (rok && (unsigned)(gcb + 0) < WW) ? o.x : 0.f;
    o.y = (rok && (unsigned)(gcb + 1) < WW) ? o.y : 0.f;
    o.z = (rok && (unsigned)(gcb + 2) < WW) ? o.z : 0.f;
    o.w = (rok && (unsigned)(gcb + 3) < WW) ? o.w : 0.f;
    st4(&sA[r * S_T + c4], o);
  }
  __syncthreads();

  // ---- P4a: sobel magnitude -> sB [66][68]; zero outside image ----
  // (cols 66,67 of each row are garbage; never read downstream)
  for (unsigned g = tid; g < 66u * 17u; g += NT) {
    unsigned r = g / 17u, k = g - r * 17u, c4 = k * 4u;
    const float* p = &sA[r * S_T + c4];
    float4 a0 = ld4(p),           b0 = ld4(p + 4);
    float4 a1 = ld4(p + S_T),     b1 = ld4(p + S_T + 4);
    float4 a2 = ld4(p + 2*S_T),   b2 = ld4(p + 2*S_T + 4);
    float e0[6] = {a0.x,a0.y,a0.z,a0.w,b0.x,b0.y};
    float e1[6] = {a1.x,a1.y,a1.z,a1.w,b1.x,b1.y};
    float e2[6] = {a2.x,a2.y,a2.z,a2.w,b2.x,b2.y};
    bool rok = (unsigned)(base_r + (int)r - 1) < HH;
    int gcb = base_c + (int)c4 - 1;
    float4 o;
    float* po = &o.x;
    #pragma unroll
    for (int j = 0; j < 4; ++j) {
      float gx = (e0[j+2]-e0[j]) + 2.f*(e1[j+2]-e1[j]) + (e2[j+2]-e2[j]);
      float gy = (e2[j]-e0[j]) + 2.f*(e2[j+1]-e0[j+1]) + (e2[j+2]-e0[j+2]);
      float m = sqrtf(gx*gx + gy*gy + 1e-12f);
      po[j] = (rok && (unsigned)(gcb + j) < WW) ? m : 0.f;
    }
    st4(&sB[r * S_T + c4], o);
  }
  __syncthreads();

  // ---- P4b+P5: column-per-lane (conflict-free), sliding 3x3 window ----
  // Wave wv covers rows wv*16..wv*16+15; lane = column. All scalar LDS
  // reads are at bank = lane + const -> 2-way max (free).
  {
    const int lane = tid & 63;
    const int wv   = tid >> 6;
    const int r0   = wv << 4;
    // center row R -> blurred tile rows R+1..R+3, cols lane+1..lane+3
    float w00,w01,w02, w10,w11,w12, w20,w21,w22;
    {
      const float* p = &sA[(r0 + 1) * S_T + lane + 1];
      w00 = p[0]; w01 = p[1]; w02 = p[2]; p += S_T;
      w10 = p[0]; w11 = p[1]; w12 = p[2]; p += S_T;
      w20 = p[0]; w21 = p[1]; w22 = p[2];
    }
    #pragma unroll
    for (int i = 0; i < 16; ++i) {
      int r = r0 + i;
      float gx = (w02 - w00) + 2.f*(w12 - w10) + (w22 - w20);
      float gy = (w20 - w00) + 2.f*(w21 - w01) + (w22 - w02);
      int rc = orient_bin(gx, gy);
      int ip = rc & 7;
      int dr = (int)((DR_PACK >> (2 * ip)) & 3u) - 1;
      int dc = (int)((DC_PACK >> (2 * ip)) & 3u) - 1;
      int ci = (r + 1) * S_T + lane + 1;
      float mcv = sB[ci];
      float n1  = sB[ci + dr * S_T + dc];
      float n2  = sB[ci - dr * S_T - dc];
      float th = (fminf(mcv - n1, mcv - n2) > 0.f) ? mcv : 0.f;
      if (ACC) {
        sAcc += fabsf(thin[i] - th);
        soAcc += abs(rcv[i] - rc);
      } else {
        thin[i] = th;
        rcv[i] = rc;
      }
      if (i < 15) {   // slide window down one row
        const float* p = &sA[(r + 4) * S_T + lane + 1];
        w00 = w10; w01 = w11; w02 = w12;
        w10 = w20; w11 = w21; w12 = w22;
        w20 = p[0]; w21 = p[1]; w22 = p[2];
      }
    }
  }
  __syncthreads();  // protect sA/sB before reuse
}

__global__ void __launch_bounds__(NT)
canny_loss_kernel(const float* __restrict__ X, const float* __restrict__ Y,
                  float* __restrict__ out, Blur5 kb)
{
  __shared__ float sA[S_IMG * S_IMG];
  __shared__ float sB[S_IMG * S_T];
  __shared__ float red[NT / 64];

  const int b = blockIdx.y;
  const int base_r = (int)(blockIdx.x >> 3) * TILE;
  const int base_c = (int)(blockIdx.x & 7) * TILE;
  const float* xb = X + (size_t)b * HH * WW;
  const float* yb = Y + (size_t)b * HH * WW;

  float thin_x[16]; int rc_x[16];
  float s = 0.f; int so = 0;
  canny_tile<false>(xb, base_r, base_c, sA, sB, kb, thin_x, rc_x, s, so);
  canny_tile<true >(yb, base_r, base_c, sA, sB, kb, thin_x, rc_x, s, so);
  s += 45.f * (float)so;

  // wave reduce (64 lanes), then cross-wave via LDS, one atomic per block
  #pragma unroll
  for (int off = 32; off >= 1; off >>= 1) s += __shfl_down(s, off, 64);
  const int lane = threadIdx.x & 63, wv = threadIdx.x >> 6;
  if (lane == 0) red[wv] = s;
  __syncthreads();
  if (threadIdx.x == 0) {
    float t = red[0] + red[1] + red[2] + red[3];
    atomicAdd(out, t * (1.0f / ((float)HH * (float)WW)));
  }
}

extern "C" void kernel_launch(void* const* d_in, const int* in_sizes, int n_in,
                              void* d_out, int out_size, void* d_ws, size_t ws_size,
                              hipStream_t stream)
{
  const float* X = (const float*)d_in[0];
  const float* Y = (const float*)d_in[1];
  float* out = (float*)d_out;

  hipMemsetAsync(out, 0, (size_t)out_size * sizeof(float), stream);

  // Gaussian 1D weights in double, cast to f32 (matches reference f64->f32 path)
  Blur5 kb;
  {
    double g[5], ssum = 0.0;
    for (int i = 0; i < 5; ++i) { double d = i - 2; g[i] = std::exp(-(d * d) / 2.0); ssum += g[i]; }
    for (int i = 0; i < 5; ++i) kb.w[i] = (float)(g[i] / ssum);
  }

  dim3 grid(64, 16);   // 8x8 tiles of 64x64 per image, 16 batch
  canny_loss_kernel<<<grid, NT, 0, stream>>>(X, Y, out, kb);
}